// Round 10
// baseline (374.909 us; speedup 1.0000x reference)
//
#include <hip/hip_runtime.h>

#define BB 4
#define NN 2048
#define CIN 256
#define HH 8
#define COUT 256
#define LOG2E 1.44269504088896340736f

// proj tiling
#define PBM 64
#define PBN 32
#define PKT 32
// attn tiling
#define TI 8          // rows per block
#define CJ 64         // j-chunk
#define JS 2          // j-split factor
#define JLEN (NN / JS)

// ---------------- Kernel 1: h = x@W + b, fused lf/ls (transposed, xlog2e) ---
// 64x32 tile (1 head per block), 4x2 micro-tile, KT=32. 1024 blocks = 4/CU.
__global__ __launch_bounds__(256) void gat_proj(
    const float* __restrict__ x, const float* __restrict__ W,
    const float* __restrict__ bias, const float* __restrict__ afst,
    const float* __restrict__ asnd, float* __restrict__ hout,
    float* __restrict__ lfT, float* __restrict__ lsT)
{
    __shared__ float xsT[PKT][PBM + 4];   // [k][row], transposed
    __shared__ float wls[PKT][PBN + 4];   // [k][col], pad kills write conflicts
    const int t = threadIdx.x;
    const int bx = blockIdx.x & 7;        // head / col tile
    const int by = blockIdx.x >> 3;       // row tile
    const int row0 = by * PBM, col0 = bx * PBN;
    const int cg = t & 15, rg = t >> 4;   // 16 col-groups(x2) , 16 row-groups(x4)

    float acc[4][2];
#pragma unroll
    for (int i = 0; i < 4; ++i) { acc[i][0] = 0.f; acc[i][1] = 0.f; }

    for (int kt = 0; kt < CIN; kt += PKT) {
#pragma unroll
        for (int s = 0; s < 2; ++s) {     // stage x tile 64x32, transposed
            const int idx = s * 256 + t;
            const int row = idx >> 3, kq = (idx & 7) * 4;
            const float4 v = *(const float4*)(x + (size_t)(row0 + row) * CIN + kt + kq);
            xsT[kq + 0][row] = v.x; xsT[kq + 1][row] = v.y;
            xsT[kq + 2][row] = v.z; xsT[kq + 3][row] = v.w;
        }
        {                                  // stage W tile 32x32
            const int k = t >> 3, c4 = (t & 7) * 4;
            *(float4*)&wls[k][c4] = *(const float4*)(W + (size_t)(kt + k) * COUT + col0 + c4);
        }
        __syncthreads();
#pragma unroll
        for (int k = 0; k < PKT; ++k) {
            const float4 xv = *(const float4*)&xsT[k][rg * 4];  // 4-addr bcast
            const float2 wv = *(const float2*)&wls[k][cg * 2];  // conflict-free
#pragma unroll
            for (int i = 0; i < 4; ++i) {
                acc[i][0] = fmaf(((const float*)&xv)[i], wv.x, acc[i][0]);
                acc[i][1] = fmaf(((const float*)&xv)[i], wv.y, acc[i][1]);
            }
        }
        __syncthreads();
    }

    // epilogue: +bias, store h, fused lf/ls dots (reduce over 16 cg lanes)
    const float2 bv = *(const float2*)(bias + col0 + cg * 2);
    const float2 af = *(const float2*)(afst + col0 + cg * 2);
    const float2 as2 = *(const float2*)(asnd + col0 + cg * 2);
    const int b = row0 >> 11;             // 64-row tile never crosses batch
    float pf[4], ps[4];
#pragma unroll
    for (int i = 0; i < 4; ++i) {
        const float o0 = acc[i][0] + bv.x, o1 = acc[i][1] + bv.y;
        const int row = row0 + rg * 4 + i;
        *(float2*)(hout + (size_t)row * COUT + col0 + cg * 2) = make_float2(o0, o1);
        pf[i] = o0 * af.x + o1 * af.y;
        ps[i] = o0 * as2.x + o1 * as2.y;
    }
#pragma unroll
    for (int off = 1; off < 16; off <<= 1) {
#pragma unroll
        for (int i = 0; i < 4; ++i) {
            pf[i] += __shfl_xor(pf[i], off);
            ps[i] += __shfl_xor(ps[i], off);
        }
    }
    if (cg == 0) {
#pragma unroll
        for (int i = 0; i < 4; ++i) {
            const int n = (row0 + rg * 4 + i) & (NN - 1);
            lfT[(size_t)(b * HH + bx) * NN + n] = pf[i] * LOG2E;  // pre-scale for exp2
            lsT[(size_t)(b * HH + bx) * NN + n] = ps[i] * LOG2E;
        }
    }
}

// e-tile word offset, layout [jl][slot], slot = float4 index 0..15.
// slot' = ((h<<1)+half) ^ (jl&7): write phase hits the 8-words/bank wave
// floor; PV read (fixed jl, 8-head broadcast) is 2-way = free. (R4: 0 confl.)
__device__ __forceinline__ int eoff4(int jl, int h, int half) {
    return jl * 64 + ((((h << 1) + half) ^ (jl & 7)) << 2);
}

// ---------------- Kernel 2: fused mask+leaky+exp partial softmax / PV ------
// One block = (b, 8-row tile, jhalf). Grid 2048 = ~6-8 blocks/CU (was 4).
// Computes UNNORMALIZED partial PV sums + partial denominators for its
// half of j; combine kernel merges. Single-pass exp (glorot-bounded logits).
__global__ __launch_bounds__(256) void gat_attn(
    const int* __restrict__ G, const float* __restrict__ hin,
    const float* __restrict__ lfT, const float* __restrict__ lsT,
    float* __restrict__ pacc0, float* __restrict__ pacc1,
    float* __restrict__ pden)
{
    __shared__ __align__(16) float e_lds[CJ * 64];   // 16KB; reused as buf
    __shared__ unsigned g_lds[4][CJ];
    __shared__ float s_lds[TI][HH];

    const int t = threadIdx.x;
    const int bi = blockIdx.x >> 1;
    const int jhalf = blockIdx.x & 1;
    const int b = bi >> 8;
    const int i0 = (bi & 255) * TI;
    const int h = t >> 5, jj = t & 31;    // e-phase mapping
    const int w = t >> 6, l = t & 63;     // PV mapping
    const int hh = l >> 3;

    float lfv[TI];
#pragma unroll
    for (int r = 0; r < TI; ++r)
        lfv[r] = lfT[(size_t)(b * HH + h) * NN + i0 + r];

    float sp[TI], a[TI][4];
#pragma unroll
    for (int r = 0; r < TI; ++r) {
        sp[r] = 0.f;
#pragma unroll
        for (int c2 = 0; c2 < 4; ++c2) a[r][c2] = 0.f;
    }

    const int jbeg = jhalf * JLEN;
    for (int j0 = jbeg; j0 < jbeg + JLEN; j0 += CJ) {
        {   // stage G: wave w covers rows 2w, 2w+1 (coalesced)
            const int col = t & 63;
            const int* gp = G + ((size_t)b * NN + i0 + 2 * w) * NN + j0 + col;
            g_lds[w][col] = (gp[0] != 0 ? 1u : 0u) | (gp[NN] != 0 ? 2u : 0u);
        }
        __syncthreads();
        // e = G ? exp2(max(s, 0.2s)) : 0, s pre-scaled by log2e
#pragma unroll
        for (int k = 0; k < CJ / 32; ++k) {
            const int jl = jj + 32 * k;
            const float lsv = lsT[(size_t)(b * HH + h) * NN + j0 + jl];  // coalesced
            const unsigned gm = g_lds[0][jl] | (g_lds[1][jl] << 2) |
                                (g_lds[2][jl] << 4) | (g_lds[3][jl] << 6);
            float ev[TI];
#pragma unroll
            for (int r = 0; r < TI; ++r) {
                float s = lfv[r] + lsv;
                s = fmaxf(s, 0.2f * s);                 // leaky-relu (scale commutes)
                ev[r] = ((gm >> r) & 1u) ? exp2f(s) : 0.f;
                sp[r] += ev[r];
            }
            *(float4*)&e_lds[eoff4(jl, h, 0)] = make_float4(ev[0], ev[1], ev[2], ev[3]);
            *(float4*)&e_lds[eoff4(jl, h, 1)] = make_float4(ev[4], ev[5], ev[6], ev[7]);
        }
        __syncthreads();
        {   // PV: wave w owns jl === w (mod 4); 1-deep hv prefetch
            const float* hbase = hin + ((size_t)b * NN + j0) * COUT + (l << 2);
            float4 hnext = *(const float4*)(hbase + (size_t)w * COUT);
#pragma unroll
            for (int it = 0; it < CJ / 4; ++it) {
                const int jl = w + it * 4;
                const float4 hv = hnext;
                if (it + 1 < CJ / 4)
                    hnext = *(const float4*)(hbase + (size_t)(jl + 4) * COUT);
                const float4 lo = *(const float4*)&e_lds[eoff4(jl, hh, 0)];
                const float4 hi = *(const float4*)&e_lds[eoff4(jl, hh, 1)];
                const float ee[8] = {lo.x, lo.y, lo.z, lo.w, hi.x, hi.y, hi.z, hi.w};
                const float hvv[4] = {hv.x, hv.y, hv.z, hv.w};
#pragma unroll
                for (int r = 0; r < TI; ++r)
#pragma unroll
                    for (int c2 = 0; c2 < 4; ++c2)
                        a[r][c2] = fmaf(ee[r], hvv[c2], a[r][c2]);
            }
        }
        __syncthreads();
    }
    // partial denominators: reduce across 32 jj-lanes per head
#pragma unroll
    for (int off = 16; off; off >>= 1) {
#pragma unroll
        for (int r = 0; r < TI; ++r) sp[r] += __shfl_xor(sp[r], off);
    }
    if (jj == 0) {
#pragma unroll
        for (int r = 0; r < TI; ++r) s_lds[r][h] = sp[r];
    }
    // cross-wave PV reduction via reused e buffer (2 partials per round)
    float* buf = e_lds;
    if (w >= 2) {
#pragma unroll
        for (int r = 0; r < TI; ++r)
#pragma unroll
            for (int c2 = 0; c2 < 4; ++c2)
                buf[((w - 2) << 11) + ((r * 4 + c2) << 6) + l] = a[r][c2];
    }
    __syncthreads();
    if (t < TI * HH)  // partial denom out
        pden[((size_t)(b * NN + i0 + (t >> 3)) * JS + jhalf) * HH + (t & 7)] =
            s_lds[t >> 3][t & 7];
    if (w < 2) {
#pragma unroll
        for (int r = 0; r < TI; ++r)
#pragma unroll
            for (int c2 = 0; c2 < 4; ++c2)
                a[r][c2] += buf[(w << 11) + ((r * 4 + c2) << 6) + l];
    }
    __syncthreads();
    if (w == 1) {
#pragma unroll
        for (int r = 0; r < TI; ++r)
#pragma unroll
            for (int c2 = 0; c2 < 4; ++c2)
                buf[((r * 4 + c2) << 6) + l] = a[r][c2];
    }
    __syncthreads();
    if (w == 0) {
        float* pa = jhalf ? pacc1 : pacc0;
#pragma unroll
        for (int r = 0; r < TI; ++r) {
            float4 o;
            o.x = a[r][0] + buf[((r * 4 + 0) << 6) + l];
            o.y = a[r][1] + buf[((r * 4 + 1) << 6) + l];
            o.z = a[r][2] + buf[((r * 4 + 2) << 6) + l];
            o.w = a[r][3] + buf[((r * 4 + 3) << 6) + l];
            *(float4*)(pa + (size_t)(b * NN + i0 + r) * COUT + (l << 2)) = o;
        }
    }
}

// ---------------- Kernel 3: combine halves + normalize ---------------------
__global__ __launch_bounds__(256) void gat_combine(
    const float* __restrict__ pacc1, const float* __restrict__ pden,
    float* __restrict__ out)  // out holds pacc0; in-place normalize
{
    const int idx = blockIdx.x * 256 + threadIdx.x;   // float4 id
    const int bi = idx >> 6;
    const int c4 = (idx & 63) * 4;
    const int h = c4 >> 5;
    const float d = pden[(size_t)bi * JS * HH + h] +
                    pden[((size_t)bi * JS + 1) * HH + h];
    const float inv = 1.f / d;
    const float4 p0 = *(const float4*)(out + (size_t)idx * 4);
    const float4 p1 = *(const float4*)(pacc1 + (size_t)idx * 4);
    float4 o;
    o.x = (p0.x + p1.x) * inv; o.y = (p0.y + p1.y) * inv;
    o.z = (p0.z + p1.z) * inv; o.w = (p0.w + p1.w) * inv;
    *(float4*)(out + (size_t)idx * 4) = o;
}

extern "C" void kernel_launch(void* const* d_in, const int* in_sizes, int n_in,
                              void* d_out, int out_size, void* d_ws, size_t ws_size,
                              hipStream_t stream) {
    const float* x    = (const float*)d_in[0];
    const int*   G    = (const int*)d_in[1];
    const float* W    = (const float*)d_in[2];
    const float* bias = (const float*)d_in[3];
    const float* afst = (const float*)d_in[4];
    const float* asnd = (const float*)d_in[5];
    float* out = (float*)d_out;

    // ws: h 8MB | lfT 256KB | lsT 256KB | pacc1 8MB | pden 512KB  (~17.8MB)
    float* h_ws   = (float*)d_ws;
    float* lfT_ws = h_ws + (size_t)BB * NN * COUT;
    float* lsT_ws = lfT_ws + (size_t)BB * HH * NN;
    float* pacc1  = lsT_ws + (size_t)BB * HH * NN;
    float* pden   = pacc1 + (size_t)BB * NN * COUT;

    hipLaunchKernelGGL(gat_proj, dim3((BB * NN / PBM) * (COUT / PBN)), dim3(256),
                       0, stream, x, W, bias, afst, asnd, h_ws, lfT_ws, lsT_ws);
    hipLaunchKernelGGL(gat_attn, dim3(BB * (NN / TI) * JS), dim3(256), 0, stream,
                       G, h_ws, lfT_ws, lsT_ws, out, pacc1, pden);
    hipLaunchKernelGGL(gat_combine, dim3(BB * NN * COUT / 4 / 256), dim3(256),
                       0, stream, pacc1, pden, out);
}

// Round 12
// 285.372 us; speedup vs baseline: 1.3138x; 1.3138x over previous
//
#include <hip/hip_runtime.h>

#define BB 4
#define NN 2048
#define CIN 256
#define HH 8
#define COUT 256
#define LOG2E 1.44269504088896340736f

// proj tiling: 128x64 tile, 8x4 micro, KT=16, double-buffered. 256 blocks.
#define PBM 128
#define PBN 64
#define PKT 16
#define NKT (CIN / PKT)
// attn tiling: 8 rows/block, 64-col chunks, full j-range per block (JS=1).
#define TI 8
#define CJ 64
#define NC (NN / CJ)

// ---------------- Kernel 1: h = x@W + b, fused lf/ls (transposed, xlog2e) ---
__global__ __launch_bounds__(256) void gat_proj(
    const float* __restrict__ x, const float* __restrict__ W,
    const float* __restrict__ bias, const float* __restrict__ afst,
    const float* __restrict__ asnd, float* __restrict__ hout,
    float* __restrict__ lfT, float* __restrict__ lsT)
{
    __shared__ float xsT[2][PKT][PBM + 4];   // [buf][k][row]
    __shared__ float wls[2][PKT][PBN + 4];   // [buf][k][col]
    const int t = threadIdx.x;
    const int bx = blockIdx.x & 3;           // col tile (2 heads)
    const int by = blockIdx.x >> 2;          // row tile
    const int row0 = by * PBM, col0 = bx * PBN;
    const int tx = t & 15, ty = t >> 4;      // 16 col-groups x4, 16 row-groups x8

    // staging: x 128x16 (2 float4/thread, transposed store), W 16x64 (1 float4)
    const int srow = t >> 2;                 // 0..63
    const int skq  = (t & 3) * 4;            // k-quad base
    const float* xb0 = x + (size_t)(row0 + srow) * CIN + skq;
    const float* xb1 = x + (size_t)(row0 + 64 + srow) * CIN + skq;
    const int swk = t >> 4, swc = (t & 15) * 4;
    const float* wb = W + (size_t)swk * COUT + col0 + swc;

    float4 xr0 = *(const float4*)xb0;
    float4 xr1 = *(const float4*)xb1;
    float4 wr  = *(const float4*)wb;
    xsT[0][skq+0][srow] = xr0.x; xsT[0][skq+1][srow] = xr0.y;
    xsT[0][skq+2][srow] = xr0.z; xsT[0][skq+3][srow] = xr0.w;
    xsT[0][skq+0][64+srow] = xr1.x; xsT[0][skq+1][64+srow] = xr1.y;
    xsT[0][skq+2][64+srow] = xr1.z; xsT[0][skq+3][64+srow] = xr1.w;
    *(float4*)&wls[0][swk][swc] = wr;
    __syncthreads();

    float acc[8][4];
#pragma unroll
    for (int i = 0; i < 8; ++i)
#pragma unroll
        for (int j = 0; j < 4; ++j) acc[i][j] = 0.f;

    for (int kt = 0; kt < NKT; ++kt) {
        if (kt + 1 < NKT) {                  // issue next-tile loads early
            xr0 = *(const float4*)(xb0 + (kt + 1) * PKT);
            xr1 = *(const float4*)(xb1 + (kt + 1) * PKT);
            wr  = *(const float4*)(wb + (size_t)(kt + 1) * PKT * COUT);
        }
        const int cur = kt & 1;
#pragma unroll
        for (int k = 0; k < PKT; ++k) {
            float xv[8], wv[4];
            *(float4*)&xv[0] = *(const float4*)&xsT[cur][k][ty * 8];     // 4-addr bcast
            *(float4*)&xv[4] = *(const float4*)&xsT[cur][k][ty * 8 + 4];
            *(float4*)&wv[0] = *(const float4*)&wls[cur][k][tx * 4];     // 2-way free
#pragma unroll
            for (int i = 0; i < 8; ++i)
#pragma unroll
                for (int j = 0; j < 4; ++j)
                    acc[i][j] = fmaf(xv[i], wv[j], acc[i][j]);
        }
        __syncthreads();
        if (kt + 1 < NKT) {                  // commit next buffer, latency hidden
            const int nxt = cur ^ 1;
            xsT[nxt][skq+0][srow] = xr0.x; xsT[nxt][skq+1][srow] = xr0.y;
            xsT[nxt][skq+2][srow] = xr0.z; xsT[nxt][skq+3][srow] = xr0.w;
            xsT[nxt][skq+0][64+srow] = xr1.x; xsT[nxt][skq+1][64+srow] = xr1.y;
            xsT[nxt][skq+2][64+srow] = xr1.z; xsT[nxt][skq+3][64+srow] = xr1.w;
            *(float4*)&wls[nxt][swk][swc] = wr;
            __syncthreads();
        }
    }

    // epilogue: +bias, store h, fused lf/ls (head = 32 cols = 8 tx lanes)
    const float4 bv = *(const float4*)(bias + col0 + tx * 4);
    const float4 af = *(const float4*)(afst + col0 + tx * 4);
    const float4 as = *(const float4*)(asnd + col0 + tx * 4);
    const int hd = (col0 + tx * 4) >> 5;
#pragma unroll
    for (int i = 0; i < 8; ++i) {
        float4 o;
        o.x = acc[i][0] + bv.x; o.y = acc[i][1] + bv.y;
        o.z = acc[i][2] + bv.z; o.w = acc[i][3] + bv.w;
        const int row = row0 + ty * 8 + i;
        *(float4*)(hout + (size_t)row * COUT + col0 + tx * 4) = o;
        float pf = o.x * af.x + o.y * af.y + o.z * af.z + o.w * af.w;
        float ps = o.x * as.x + o.y * as.y + o.z * as.z + o.w * as.w;
#pragma unroll
        for (int off = 1; off < 8; off <<= 1) {
            pf += __shfl_xor(pf, off);
            ps += __shfl_xor(ps, off);
        }
        if ((tx & 7) == 0) {
            const int b = row >> 11, n = row & (NN - 1);
            lfT[(size_t)(b * HH + hd) * NN + n] = pf * LOG2E;  // pre-scale for exp2
            lsT[(size_t)(b * HH + hd) * NN + n] = ps * LOG2E;
        }
    }
}

// e-tile word offset, layout [jl][slot]; slot'=((h<<1)+half)^(jl&7).
// Writes hit the 8-words/bank wave floor; PV reads are broadcast. (R4: 0 confl.)
__device__ __forceinline__ int eoff4(int jl, int h, int half) {
    return jl * 64 + ((((h << 1) + half) ^ (jl & 7)) << 2);
}

// ---------------- Kernel 2: fused mask+leaky+exp softmax / PV --------------
// One block = (b, 8 rows), full j-range, grid 1024. Register-prefetched
// G/lsT (1 chunk ahead, issued during PV) + 4-deep hv prefetch: per-wave
// dependency chains now covered by in-flight loads instead of stalls.
__global__ __launch_bounds__(256) void gat_attn(
    const int* __restrict__ G, const float* __restrict__ hin,
    const float* __restrict__ lfT, const float* __restrict__ lsT,
    float* __restrict__ out)
{
    __shared__ __align__(16) float e_lds[CJ * 64];   // 16KB; reused as buf
    __shared__ unsigned g_lds[4][CJ];
    __shared__ float s_lds[TI][HH];

    const int t = threadIdx.x;
    const int b = blockIdx.x >> 8;
    const int i0 = (blockIdx.x & 255) * TI;
    const int h = t >> 5, jj = t & 31;    // e-phase mapping
    const int w = t >> 6, l = t & 63;     // PV mapping
    const int hh = l >> 3;

    const float* lsrow = lsT + (size_t)(b * HH + h) * NN;
    float lfv[TI];
#pragma unroll
    for (int r = 0; r < TI; ++r)
        lfv[r] = lfT[(size_t)(b * HH + h) * NN + i0 + r];

    float sp[TI], a[TI][4];
#pragma unroll
    for (int r = 0; r < TI; ++r) {
        sp[r] = 0.f;
#pragma unroll
        for (int c2 = 0; c2 < 4; ++c2) a[r][c2] = 0.f;
    }

    // prefetch chunk 0: G rows 2w,2w+1 at col l; lsT at (h, jj/jj+32)
    const int* gbase = G + ((size_t)b * NN + i0 + 2 * w) * NN + l;
    int g0 = gbase[0], g1 = gbase[NN];
    float ls0 = lsrow[jj], ls1 = lsrow[32 + jj];

    for (int c = 0; c < NC; ++c) {
        const int j0 = c * CJ;
        g_lds[w][l] = (g0 ? 1u : 0u) | (g1 ? 2u : 0u);   // commit prefetched G
        __syncthreads();
        // e = G ? exp2(max(s,0.2s)) : 0 (s pre-scaled by log2e); regs only
        {
            const unsigned gmA = g_lds[0][jj] | (g_lds[1][jj] << 2) |
                                 (g_lds[2][jj] << 4) | (g_lds[3][jj] << 6);
            const unsigned gmB = g_lds[0][jj+32] | (g_lds[1][jj+32] << 2) |
                                 (g_lds[2][jj+32] << 4) | (g_lds[3][jj+32] << 6);
            float ev[TI];
#pragma unroll
            for (int r = 0; r < TI; ++r) {
                float s = lfv[r] + ls0;
                s = fmaxf(s, 0.2f * s);
                ev[r] = ((gmA >> r) & 1u) ? exp2f(s) : 0.f;
                sp[r] += ev[r];
            }
            *(float4*)&e_lds[eoff4(jj, h, 0)] = make_float4(ev[0], ev[1], ev[2], ev[3]);
            *(float4*)&e_lds[eoff4(jj, h, 1)] = make_float4(ev[4], ev[5], ev[6], ev[7]);
#pragma unroll
            for (int r = 0; r < TI; ++r) {
                float s = lfv[r] + ls1;
                s = fmaxf(s, 0.2f * s);
                ev[r] = ((gmB >> r) & 1u) ? exp2f(s) : 0.f;
                sp[r] += ev[r];
            }
            *(float4*)&e_lds[eoff4(jj+32, h, 0)] = make_float4(ev[0], ev[1], ev[2], ev[3]);
            *(float4*)&e_lds[eoff4(jj+32, h, 1)] = make_float4(ev[4], ev[5], ev[6], ev[7]);
        }
        __syncthreads();
        // issue next chunk's G + lsT loads (consumed after next barrier)
        if (c + 1 < NC) {
            const int* gp = gbase + (size_t)(j0 + CJ);
            g0 = gp[0]; g1 = gp[NN];
            ls0 = lsrow[j0 + CJ + jj]; ls1 = lsrow[j0 + CJ + 32 + jj];
        }
        // PV: wave w owns jl === w (mod 4); 4-deep rolling hv prefetch
        {
            const float* hbase = hin + ((size_t)b * NN + j0) * COUT + (l << 2);
            float4 hq[4];
#pragma unroll
            for (int p = 0; p < 4; ++p)
                hq[p] = *(const float4*)(hbase + (size_t)(w + p * 4) * COUT);
#pragma unroll
            for (int it = 0; it < CJ / 4; ++it) {
                const int jl = w + it * 4;
                const float4 hv = hq[it & 3];
                if (it + 4 < CJ / 4)
                    hq[it & 3] = *(const float4*)(hbase + (size_t)(jl + 16) * COUT);
                const float4 lo = *(const float4*)&e_lds[eoff4(jl, hh, 0)];
                const float4 hi = *(const float4*)&e_lds[eoff4(jl, hh, 1)];
                const float ee[8] = {lo.x, lo.y, lo.z, lo.w, hi.x, hi.y, hi.z, hi.w};
                const float hvv[4] = {hv.x, hv.y, hv.z, hv.w};
#pragma unroll
                for (int r = 0; r < TI; ++r)
#pragma unroll
                    for (int c2 = 0; c2 < 4; ++c2)
                        a[r][c2] = fmaf(ee[r], hvv[c2], a[r][c2]);
            }
        }
        __syncthreads();
    }
    // softmax denominators: reduce across the 32 jj-lanes of each head
#pragma unroll
    for (int off = 16; off; off >>= 1) {
#pragma unroll
        for (int r = 0; r < TI; ++r) sp[r] += __shfl_xor(sp[r], off);
    }
    if (jj == 0) {
#pragma unroll
        for (int r = 0; r < TI; ++r) s_lds[r][h] = sp[r];
    }
    // cross-wave PV reduction through reused e buffer, then normalized write
    float* buf = e_lds;
    if (w >= 2) {
#pragma unroll
        for (int r = 0; r < TI; ++r)
#pragma unroll
            for (int c2 = 0; c2 < 4; ++c2)
                buf[((w - 2) << 11) + ((r * 4 + c2) << 6) + l] = a[r][c2];
    }
    __syncthreads();
    if (w < 2) {
#pragma unroll
        for (int r = 0; r < TI; ++r)
#pragma unroll
            for (int c2 = 0; c2 < 4; ++c2)
                a[r][c2] += buf[(w << 11) + ((r * 4 + c2) << 6) + l];
    }
    __syncthreads();
    if (w == 1) {
#pragma unroll
        for (int r = 0; r < TI; ++r)
#pragma unroll
            for (int c2 = 0; c2 < 4; ++c2)
                buf[((r * 4 + c2) << 6) + l] = a[r][c2];
    }
    __syncthreads();
    if (w == 0) {
#pragma unroll
        for (int r = 0; r < TI; ++r) {
            const float inv = 1.f / s_lds[r][hh];
            float4 o;
            o.x = (a[r][0] + buf[((r * 4 + 0) << 6) + l]) * inv;
            o.y = (a[r][1] + buf[((r * 4 + 1) << 6) + l]) * inv;
            o.z = (a[r][2] + buf[((r * 4 + 2) << 6) + l]) * inv;
            o.w = (a[r][3] + buf[((r * 4 + 3) << 6) + l]) * inv;
            *(float4*)(out + (size_t)(b * NN + i0 + r) * COUT + (l << 2)) = o;
        }
    }
}

extern "C" void kernel_launch(void* const* d_in, const int* in_sizes, int n_in,
                              void* d_out, int out_size, void* d_ws, size_t ws_size,
                              hipStream_t stream) {
    const float* x    = (const float*)d_in[0];
    const int*   G    = (const int*)d_in[1];
    const float* W    = (const float*)d_in[2];
    const float* bias = (const float*)d_in[3];
    const float* afst = (const float*)d_in[4];
    const float* asnd = (const float*)d_in[5];
    float* out = (float*)d_out;

    // ws: h 8MB | lfT 256KB | lsT 256KB
    float* h_ws   = (float*)d_ws;
    float* lfT_ws = h_ws + (size_t)BB * NN * COUT;
    float* lsT_ws = lfT_ws + (size_t)BB * HH * NN;

    hipLaunchKernelGGL(gat_proj, dim3((BB * NN / PBM) * (COUT / PBN)), dim3(256),
                       0, stream, x, W, bias, afst, asnd, h_ws, lfT_ws, lsT_ws);
    hipLaunchKernelGGL(gat_attn, dim3(BB * (NN / TI)), dim3(256), 0, stream,
                       G, h_ws, lfT_ws, lsT_ws, out);
}